// Round 10
// baseline (53.927 us; speedup 1.0000x reference)
//
#include <hip/hip_runtime.h>
#include <hip/hip_bf16.h>
#include <stdint.h>

#define Kdim 2048
#define Vdim 768
#define Mdim 4096   // B*N = 16*256

#define BMx 128
#define BNx 128
#define BKx 64
#define NTx (Vdim / BKx)   // 12 K-steps
#define PIPE 4             // LDS pipeline depth (stage 3 ahead)
#define NBLK 512

typedef __attribute__((ext_vector_type(4))) int  i32x4;
typedef __attribute__((ext_vector_type(16))) int i32x16;

#define CFENCE asm volatile("" ::: "memory")

__device__ __forceinline__ void gld_lds16(const void* g, void* l) {
    __builtin_amdgcn_global_load_lds((const __attribute__((address_space(1))) void*)g,
                                     (__attribute__((address_space(3))) void*)l, 16, 0, 0);
}

// ONE kernel, grid 512x256, all co-resident (64KB LDS + launch_bounds(256,2)
// -> exactly 2 blocks/CU x 256 CU = 512).
// Panel-granular producer/consumer (NO global barrier):
//   block (bm,bn) quantizes 8 rows of A-panel bm + 4 rows of P-panel bn
//   (+ proto fp32 pass-through), then waits only for its two panels:
//   cntA[bm]==16, cntP[bn]==32. RELAXED spin + s_sleep (R8's per-iteration
//   ACQUIRE spin caused an invalidate storm, ~60us); single ACQUIRE after.
// T1 swizzle makes all 16 consumers of A-panel bm live on one XCD -> the
// producers ARE the consumers -> Aq panel stays in the local L2.
// GEMM phase: R9 verbatim (PIPE=4, counted vmcnt(8), XOR swizzle, setprio).
__global__ __launch_bounds__(256, 2) void fused_dist(const float* __restrict__ x,
                                                     const float* __restrict__ p,
                                                     int8_t* __restrict__ Aq,
                                                     int8_t* __restrict__ Pq,
                                                     float* __restrict__ xsq,
                                                     float* __restrict__ psq,
                                                     float* __restrict__ sxa,
                                                     float* __restrict__ spa,
                                                     unsigned int* __restrict__ cnt,
                                                     float* __restrict__ out) {
    __shared__ int8_t As[PIPE][BMx * BKx];   // 4 x 8KB
    __shared__ int8_t Bs[PIPE][BNx * BKx];   // 4 x 8KB

    const int t = threadIdx.x;
    const int lane = t & 63;
    const int wave = t >> 6;       // 0..3
    const int xcd = blockIdx.x & 7;
    const int seq = blockIdx.x >> 3;

    // T1: bijective XCD swizzle; XCD x owns bm in [4x, 4x+4)
    const int wg = xcd * 64 + seq;
    const int bm = wg >> 4;        // 0..31
    const int bn = wg & 15;        // 0..15
    const int m0 = bm * BMx, n0 = bn * BNx;

    unsigned int* cA = cnt + (size_t)bm * 16;          // 64B-padded counters
    unsigned int* cP = cnt + (size_t)(32 + bn) * 16;

    // ================= Phase 1: quantize own panels =================
    {
        auto dorow = [&](const float* src, int8_t* dq, float* sq, float* sc, float* cpy) {
            float4 v[3];
            float s = 0.f, mx = 0.f;
#pragma unroll
            for (int c = 0; c < 3; ++c) {
                v[c] = *reinterpret_cast<const float4*>(src + c * 256 + lane * 4);
                s += v[c].x * v[c].x + v[c].y * v[c].y + v[c].z * v[c].z + v[c].w * v[c].w;
                mx = fmaxf(mx, fmaxf(fmaxf(fabsf(v[c].x), fabsf(v[c].y)),
                                     fmaxf(fabsf(v[c].z), fabsf(v[c].w))));
                if (cpy) *reinterpret_cast<float4*>(cpy + c * 256 + lane * 4) = v[c];
            }
#pragma unroll
            for (int off = 32; off > 0; off >>= 1) {
                s += __shfl_xor(s, off);
                mx = fmaxf(mx, __shfl_xor(mx, off));
            }
            mx = fmaxf(mx, 1e-20f);
            const float inv = 127.0f / mx;
#pragma unroll
            for (int c = 0; c < 3; ++c) {
                int q0 = min(127, max(-127, __float2int_rn(v[c].x * inv)));
                int q1 = min(127, max(-127, __float2int_rn(v[c].y * inv)));
                int q2 = min(127, max(-127, __float2int_rn(v[c].z * inv)));
                int q3 = min(127, max(-127, __float2int_rn(v[c].w * inv)));
                int packed = (q0 & 0xff) | ((q1 & 0xff) << 8) | ((q2 & 0xff) << 16) | (q3 << 24);
                *reinterpret_cast<int*>(dq + c * 256 + lane * 4) = packed;
            }
            if (lane == 0) { *sq = s; *sc = mx * (1.0f / 127.0f); }
        };

        // 2 A-rows of panel bm per wave (block covers rows m0+bn*8 .. +8)
        const int ar = m0 + bn * 8 + wave * 2;
        dorow(x + (size_t)ar * Vdim, Aq + (size_t)ar * Vdim, xsq + ar, sxa + ar, nullptr);
        dorow(x + (size_t)(ar + 1) * Vdim, Aq + (size_t)(ar + 1) * Vdim,
              xsq + ar + 1, sxa + ar + 1, nullptr);
        // 1 P-row of panel bn per wave (block covers rows n0+bm*4 .. +4)
        const int pr = n0 + bm * 4 + wave;
        dorow(p + (size_t)pr * Vdim, Pq + (size_t)pr * Vdim, psq + pr, spa + pr,
              out + (size_t)Mdim * Kdim + (size_t)pr * Vdim);
    }

    // ================= Panel sync (lean) =================
    __syncthreads();   // all waves' stores drained (vmcnt(0) before s_barrier)
    if (t == 0) {
        __hip_atomic_fetch_add(cA, 1u, __ATOMIC_RELEASE, __HIP_MEMORY_SCOPE_AGENT);
        __hip_atomic_fetch_add(cP, 1u, __ATOMIC_RELEASE, __HIP_MEMORY_SCOPE_AGENT);
        while (__hip_atomic_load(cA, __ATOMIC_RELAXED, __HIP_MEMORY_SCOPE_AGENT) < 16u)
            __builtin_amdgcn_s_sleep(4);
        while (__hip_atomic_load(cP, __ATOMIC_RELAXED, __HIP_MEMORY_SCOPE_AGENT) < 32u)
            __builtin_amdgcn_s_sleep(4);
        (void)__hip_atomic_load(cA, __ATOMIC_ACQUIRE, __HIP_MEMORY_SCOPE_AGENT);  // one acquire
    }
    __syncthreads();

    // ================= Phase 2: GEMM (R9 structure) =================
    const int wr = wave >> 1;      // 0..1 (M)
    const int wc = wave & 1;       // 0..1 (N)
    const int ln31 = lane & 31;
    const int lh = lane >> 5;      // 0..1

    const int srow = t >> 2;                               // 0..63
    const int scol = ((t & 3) ^ ((srow >> 1) & 3)) * 16;   // inverse-swizzled source
    const int8_t* Ag = Aq + (size_t)(m0 + srow) * Vdim + scol;
    const int8_t* Bg = Pq + (size_t)(n0 + srow) * Vdim + scol;
    const int ldsoff = wave * 1024;

    int offA[2][2], offB[2][2];
#pragma unroll
    for (int mt = 0; mt < 2; ++mt)
#pragma unroll
        for (int ks = 0; ks < 2; ++ks) {
            const int S = ks * 2 + lh;
            const int rA = wr * 64 + mt * 32 + ln31;
            const int rB = wc * 64 + mt * 32 + ln31;
            offA[mt][ks] = rA * BKx + ((S ^ ((rA >> 1) & 3)) * 16);
            offB[mt][ks] = rB * BKx + ((S ^ ((rB >> 1) & 3)) * 16);
        }

    auto stage = [&](int buf, int kt) {
#pragma unroll
        for (int q = 0; q < 2; ++q)
            gld_lds16(Ag + (size_t)q * 64 * Vdim + kt * BKx, (void*)(&As[buf][q * 4096 + ldsoff]));
#pragma unroll
        for (int q = 0; q < 2; ++q)
            gld_lds16(Bg + (size_t)q * 64 * Vdim + kt * BKx, (void*)(&Bs[buf][q * 4096 + ldsoff]));
    };

    i32x16 acc[2][2] = {};

    stage(0, 0); stage(1, 1); stage(2, 2);
    asm volatile("s_waitcnt vmcnt(8)" ::: "memory");
    __builtin_amdgcn_s_barrier();
    CFENCE;

    for (int kt = 0; kt < NTx; ++kt) {
        const int cb = kt & 3;
        if (kt + 3 < NTx) stage((kt + 3) & 3, kt + 3);   // 3-ahead prefetch

        const int8_t* Ap = &As[cb][0];
        const int8_t* Bp = &Bs[cb][0];
        i32x4 af[2][2], bf[2][2];
#pragma unroll
        for (int mt = 0; mt < 2; ++mt)
#pragma unroll
            for (int ks = 0; ks < 2; ++ks) {
                af[mt][ks] = *reinterpret_cast<const i32x4*>(Ap + offA[mt][ks]);
                bf[mt][ks] = *reinterpret_cast<const i32x4*>(Bp + offB[mt][ks]);
            }
        CFENCE;
        __builtin_amdgcn_s_setprio(1);
#pragma unroll
        for (int ks = 0; ks < 2; ++ks)
#pragma unroll
            for (int mt = 0; mt < 2; ++mt)
#pragma unroll
                for (int nt = 0; nt < 2; ++nt)
                    acc[mt][nt] = __builtin_amdgcn_mfma_i32_32x32x32_i8(af[mt][ks], bf[nt][ks], acc[mt][nt], 0, 0, 0);
        __builtin_amdgcn_s_setprio(0);
        CFENCE;
        if (kt <= NTx - 4)      asm volatile("s_waitcnt vmcnt(8)" ::: "memory");
        else if (kt == NTx - 3) asm volatile("s_waitcnt vmcnt(4)" ::: "memory");
        else if (kt == NTx - 2) asm volatile("s_waitcnt vmcnt(0)" ::: "memory");
        if (kt + 1 < NTx) { __builtin_amdgcn_s_barrier(); CFENCE; }
    }

    // Epilogue. 32x32 C/D layout: col=lane&31, row=(reg&3)+8*(reg>>2)+4*(lane>>5).
    float ps_[2], sp_[2];
    int col_[2];
#pragma unroll
    for (int nt = 0; nt < 2; ++nt) {
        col_[nt] = n0 + wc * 64 + nt * 32 + ln31;
        ps_[nt] = psq[col_[nt]];
        sp_[nt] = spa[col_[nt]];
    }
#pragma unroll
    for (int mt = 0; mt < 2; ++mt)
#pragma unroll
        for (int reg = 0; reg < 16; ++reg) {
            const int row = m0 + wr * 64 + mt * 32 + (reg & 3) + 8 * (reg >> 2) + 4 * lh;
            const float xs = xsq[row];
            const float m2sx = -2.0f * sxa[row];
#pragma unroll
            for (int nt = 0; nt < 2; ++nt)
                out[(size_t)row * Kdim + col_[nt]] =
                    xs + ps_[nt] + m2sx * sp_[nt] * (float)acc[mt][nt][reg];
        }
}

extern "C" void kernel_launch(void* const* d_in, const int* in_sizes, int n_in,
                              void* d_out, int out_size, void* d_ws, size_t ws_size,
                              hipStream_t stream) {
    const float* x = (const float*)d_in[0];   // (16,256,768) fp32
    const float* p = (const float*)d_in[1];   // (2048,768) fp32
    float* out = (float*)d_out;               // distances (4096x2048) + prototypes (2048x768)

    char* ws = (char*)d_ws;
    int8_t* Aq = (int8_t*)ws;                          // 3,145,728 B
    int8_t* Pq = (int8_t*)(ws + 3145728);              // 1,572,864 B
    float* xsq = (float*)(ws + 4718592);               // 16,384 B
    float* psq = (float*)(ws + 4734976);               // 8,192 B
    float* sxa = (float*)(ws + 4743168);               // 16,384 B
    float* spa = (float*)(ws + 4759552);               // 8,192 B
    unsigned int* cnt = (unsigned int*)(ws + 4767744); // 48 x 64B counters

    hipMemsetAsync((void*)cnt, 0, 48 * 64, stream);    // deterministic across replays
    fused_dist<<<NBLK, 256, 0, stream>>>(x, p, Aq, Pq, xsq, psq, sxa, spa, cnt, out);
}

// Round 11
// 33.941 us; speedup vs baseline: 1.5888x; 1.5888x over previous
//
#include <hip/hip_runtime.h>
#include <hip/hip_bf16.h>
#include <stdint.h>

#define Kdim 2048
#define Vdim 768
#define Mdim 4096   // B*N = 16*256

#define NT 12       // K-steps of 64 fp32 elems

typedef __attribute__((ext_vector_type(8))) short short8;
typedef __attribute__((ext_vector_type(16))) float f32x16;

#define CFENCE asm volatile("" ::: "memory")

struct alignas(8) B4 { __hip_bfloat16 a, b, c, d; };

// ONE kernel, 512 blocks x 256 threads, ZERO inter-block dependencies.
// Block (bm,bn) computes dist tile [128m x 128k]:
//  - stages fp32 x/p tiles global->reg (coalesced float4), converts bf16,
//    ds_writes into XOR-8 swizzled LDS (both-sides swizzle, proven pattern)
//  - accumulates per-row fp32 sumsq during staging (thread-owned row chunks),
//    LDS-reduced after the K-loop  -> no producer kernel, no sync, no ws
//  - 16x mfma_f32_32x32x16_bf16 per K-step, double-buffered LDS (64KB ->
//    2 blocks/CU), 1-step-ahead register prefetch, raw s_barrier (loads in
//    flight stay in VGPRs -> no vmcnt drain needed at barriers)
//  - fused distance epilogue + proto fp32 passthrough (4 rows/block, L2-hot)
__global__ __launch_bounds__(256, 2) void fused_dist(const float* __restrict__ x,
                                                     const float* __restrict__ p,
                                                     float* __restrict__ out) {
    __shared__ __hip_bfloat16 Asb[2][128 * 64];   // 2 x 16KB
    __shared__ __hip_bfloat16 Bsb[2][128 * 64];   // 2 x 16KB

    const int t = threadIdx.x;
    const int lane = t & 63;
    const int wave = t >> 6;       // 0..3
    const int wr = wave >> 1;      // 0..1 (M)
    const int wc = wave & 1;       // 0..1 (N)
    const int ln31 = lane & 31;
    const int lh = lane >> 5;

    // XCD-bijective swizzle (512 % 8 == 0)
    const int wg = (blockIdx.x & 7) * 64 + (blockIdx.x >> 3);
    const int bm = wg >> 4, bn = wg & 15;
    const int m0 = bm * 128, n0 = bn * 128;

    // ---- staging mapping: thread t -> row-group rg (0..15), 4-float chunk c16
    // rows r_j = rg + 16j (j=0..7); fully coalesced: 16 consecutive threads
    // read 256B contiguous per row.
    const int rg = t >> 4;
    const int c16 = t & 15;
    const float* Axp = x + (size_t)(m0 + rg) * Vdim + c16 * 4;
    const float* Bxp = p + (size_t)(n0 + rg) * Vdim + c16 * 4;

    // LDS write byte offsets (bf16 tile [128 rows][128B], slot16 ^= row&7)
    int woff[8];
#pragma unroll
    for (int j = 0; j < 8; ++j) {
        const int r = rg + 16 * j;
        woff[j] = r * 128 + (((c16 >> 1) ^ (r & 7)) << 4) + (c16 & 1) * 8;
    }

    // frag read byte offsets: row r, logical slot S=ks*2+lh, phys = S^(r&7)
    int offA[2][4], offB[2][4];
#pragma unroll
    for (int mt = 0; mt < 2; ++mt)
#pragma unroll
        for (int ks = 0; ks < 4; ++ks) {
            const int S = ks * 2 + lh;
            const int rA = wr * 64 + mt * 32 + ln31;
            const int rB = wc * 64 + mt * 32 + ln31;
            offA[mt][ks] = rA * 128 + ((S ^ (rA & 7)) << 4);
            offB[mt][ks] = rB * 128 + ((S ^ (rB & 7)) << 4);
        }

    float4 pa[8], pb[8];                  // 1-step-ahead prefetch regs
    float aacc[8] = {0, 0, 0, 0, 0, 0, 0, 0};
    float bacc[8] = {0, 0, 0, 0, 0, 0, 0, 0};
    f32x16 acc[2][2] = {};

    auto LOAD = [&](int kt) {
#pragma unroll
        for (int j = 0; j < 8; ++j) {
            pa[j] = *reinterpret_cast<const float4*>(Axp + (size_t)(16 * j) * Vdim + kt * 64);
            pb[j] = *reinterpret_cast<const float4*>(Bxp + (size_t)(16 * j) * Vdim + kt * 64);
        }
    };
    auto QW = [&](int buf) {   // quantize + sumsq + swizzled ds_write
        char* As = reinterpret_cast<char*>(&Asb[buf][0]);
        char* Bsl = reinterpret_cast<char*>(&Bsb[buf][0]);
#pragma unroll
        for (int j = 0; j < 8; ++j) {
            float4 v = pa[j];
            aacc[j] = fmaf(v.x, v.x, fmaf(v.y, v.y, fmaf(v.z, v.z, fmaf(v.w, v.w, aacc[j]))));
            B4 w;
            w.a = __float2bfloat16(v.x); w.b = __float2bfloat16(v.y);
            w.c = __float2bfloat16(v.z); w.d = __float2bfloat16(v.w);
            *reinterpret_cast<B4*>(As + woff[j]) = w;
            float4 u = pb[j];
            bacc[j] = fmaf(u.x, u.x, fmaf(u.y, u.y, fmaf(u.z, u.z, fmaf(u.w, u.w, bacc[j]))));
            B4 z;
            z.a = __float2bfloat16(u.x); z.b = __float2bfloat16(u.y);
            z.c = __float2bfloat16(u.z); z.d = __float2bfloat16(u.w);
            *reinterpret_cast<B4*>(Bsl + woff[j]) = z;
        }
    };

    // ---- prologue
    LOAD(0);
    QW(0);            // compiler inserts the vmcnt waits on pa/pb
    LOAD(1);
    asm volatile("s_waitcnt lgkmcnt(0)" ::: "memory");
    __builtin_amdgcn_s_barrier();
    CFENCE;

    // ---- K-loop: one barrier per step; global loads stay in flight across it
    for (int kt = 0; kt < NT; ++kt) {
        const int cb = kt & 1;
        if (kt + 1 < NT) QW(cb ^ 1);      // consume regs (kt+1) -> other buffer
        if (kt + 2 < NT) LOAD(kt + 2);    // refill regs, ~1 full step of cover
        CFENCE;

        const char* Ap = reinterpret_cast<const char*>(&Asb[cb][0]);
        const char* Bp = reinterpret_cast<const char*>(&Bsb[cb][0]);
        __builtin_amdgcn_s_setprio(1);
#pragma unroll
        for (int ks = 0; ks < 4; ++ks) {
            short8 af0 = *reinterpret_cast<const short8*>(Ap + offA[0][ks]);
            short8 af1 = *reinterpret_cast<const short8*>(Ap + offA[1][ks]);
            short8 bf0 = *reinterpret_cast<const short8*>(Bp + offB[0][ks]);
            short8 bf1 = *reinterpret_cast<const short8*>(Bp + offB[1][ks]);
            acc[0][0] = __builtin_amdgcn_mfma_f32_32x32x16_bf16(af0, bf0, acc[0][0], 0, 0, 0);
            acc[0][1] = __builtin_amdgcn_mfma_f32_32x32x16_bf16(af0, bf1, acc[0][1], 0, 0, 0);
            acc[1][0] = __builtin_amdgcn_mfma_f32_32x32x16_bf16(af1, bf0, acc[1][0], 0, 0, 0);
            acc[1][1] = __builtin_amdgcn_mfma_f32_32x32x16_bf16(af1, bf1, acc[1][1], 0, 0, 0);
        }
        __builtin_amdgcn_s_setprio(0);
        CFENCE;
        asm volatile("s_waitcnt lgkmcnt(0)" ::: "memory");
        __builtin_amdgcn_s_barrier();     // NO vmcnt drain: in-flight loads are reg-private
        CFENCE;
    }

    // ---- proto fp32 passthrough (rows n0+bm*4 .. +4; L2-hot from B staging)
    {
        const int prow = n0 + bm * 4 + wave;
        const float* srcp = p + (size_t)prow * Vdim;
        float* dstp = out + (size_t)Mdim * Kdim + (size_t)prow * Vdim;
#pragma unroll
        for (int i = 0; i < 3; ++i)
            *reinterpret_cast<float4*>(dstp + i * 256 + lane * 4) =
                *reinterpret_cast<const float4*>(srcp + i * 256 + lane * 4);
    }

    // ---- sumsq reduction through LDS (Asb/Bsb are dead now; barrier passed)
    float* scr = reinterpret_cast<float*>(&Asb[0][0]);    // [128][16] A + [128][16] B
#pragma unroll
    for (int j = 0; j < 8; ++j) {
        scr[(rg + 16 * j) * 16 + c16] = aacc[j];
        scr[2048 + (rg + 16 * j) * 16 + c16] = bacc[j];
    }
    asm volatile("s_waitcnt lgkmcnt(0)" ::: "memory");
    __builtin_amdgcn_s_barrier();
    float* rowsum = reinterpret_cast<float*>(&Bsb[0][0]); // [0,128)=xsq, [128,256)=psq
    {
        const float* base = scr + (t < 128 ? t * 16 : 2048 + (t - 128) * 16);
        float s = 0.f;
#pragma unroll
        for (int c = 0; c < 16; ++c) s += base[c];
        rowsum[t] = s;
    }
    asm volatile("s_waitcnt lgkmcnt(0)" ::: "memory");
    __builtin_amdgcn_s_barrier();

    // ---- epilogue. 32x32 C/D: col=lane&31, row=(reg&3)+8*(reg>>2)+4*(lane>>5)
    float ps_[2];
    int col_[2];
#pragma unroll
    for (int nt = 0; nt < 2; ++nt) {
        const int cl = wc * 64 + nt * 32 + ln31;
        col_[nt] = n0 + cl;
        ps_[nt] = rowsum[128 + cl];
    }
#pragma unroll
    for (int mt = 0; mt < 2; ++mt)
#pragma unroll
        for (int reg = 0; reg < 16; ++reg) {
            const int rowl = wr * 64 + mt * 32 + (reg & 3) + 8 * (reg >> 2) + 4 * lh;
            const float xs = rowsum[rowl];
#pragma unroll
            for (int nt = 0; nt < 2; ++nt)
                out[(size_t)(m0 + rowl) * Kdim + col_[nt]] =
                    xs + ps_[nt] - 2.0f * acc[mt][nt][reg];
        }
}

extern "C" void kernel_launch(void* const* d_in, const int* in_sizes, int n_in,
                              void* d_out, int out_size, void* d_ws, size_t ws_size,
                              hipStream_t stream) {
    const float* x = (const float*)d_in[0];   // (16,256,768) fp32
    const float* p = (const float*)d_in[1];   // (2048,768) fp32
    float* out = (float*)d_out;               // distances (4096x2048) + prototypes (2048x768)

    fused_dist<<<512, 256, 0, stream>>>(x, p, out);
}

// Round 12
// 33.855 us; speedup vs baseline: 1.5929x; 1.0025x over previous
//
#include <hip/hip_runtime.h>
#include <hip/hip_bf16.h>
#include <stdint.h>

#define Kdim 2048
#define Vdim 768
#define Mdim 4096   // B*N = 16*256

#define NT 12       // K-steps of 64 fp32 elems

typedef __attribute__((ext_vector_type(8))) short short8;
typedef __attribute__((ext_vector_type(16))) float f32x16;

#define CFENCE asm volatile("" ::: "memory")

struct alignas(8) B4 { __hip_bfloat16 a, b, c, d; };

// ONE kernel, 256 blocks x 512 threads (1 block/CU), ZERO inter-block deps.
// Tile 256m x 128k: redundant fp32 reads = 16*|x| + 16*|p| = 201 MB (half of
// R11's 402), with per-XCD mapping keeping the 2 A-panels L2-resident and
// p-panels visited by consecutive blocks. Ping-pong named register sets give
// the global loads a full QW+MFMA phase of latency cover. Staging converts
// fp32->bf16 into XOR-8 swizzled LDS (R11-verified layout), accumulates row
// sumsq in fp32 on the fly; LDS-reduced at the end (stride-17, conflict-free).
__global__ __launch_bounds__(512, 1) void fused_dist(const float* __restrict__ x,
                                                     const float* __restrict__ p,
                                                     float* __restrict__ out) {
    __shared__ char lds[98304];
    // A bufs: 0, 32768  (256 rows x 128B each)
    // B bufs: 65536, 81920 (128 rows x 128B each)

    const int t = threadIdx.x;
    const int lane = t & 63;
    const int wave = t >> 6;        // 0..7
    const int wr = wave >> 1;       // 0..3 (M)
    const int wc = wave & 1;        // 0..1 (N)
    const int ln31 = lane & 31;
    const int lh = lane >> 5;

    // XCD mapping: XCD x owns bm in {2x, 2x+1} (alternating fast -> both
    // A-panels stay L2-hot); bn advances every 2 blocks (consecutive p-panel
    // visits back-to-back -> one L3 fetch per panel per XCD).
    const int xcd = blockIdx.x & 7, seq = blockIdx.x >> 3;
    const int bn = seq >> 1;                  // 0..15
    const int bm = 2 * xcd + (seq & 1);       // 0..15
    const int m0 = bm * 256, n0 = bn * 128;

    // staging: thread t -> rowgroup rg (0..31), 16B chunk c16 (16 thr/row)
    const int rg = t >> 4;
    const int c16 = t & 15;
    const float* Axp = x + (size_t)(m0 + rg) * Vdim + c16 * 4;  // rows rg+32j, j<8
    const float* Bxp = p + (size_t)(n0 + rg) * Vdim + c16 * 4;  // rows rg+32j, j<4

    // LDS write offsets (tile [rows][128B], 16B-slot ^= row&7; verified R11)
    int woffA[8], woffB[4];
#pragma unroll
    for (int j = 0; j < 8; ++j) {
        const int r = rg + 32 * j;
        woffA[j] = r * 128 + (((c16 >> 1) ^ (r & 7)) << 4) + (c16 & 1) * 8;
    }
#pragma unroll
    for (int j = 0; j < 4; ++j) {
        const int r = rg + 32 * j;
        woffB[j] = r * 128 + (((c16 >> 1) ^ (r & 7)) << 4) + (c16 & 1) * 8;
    }

    // fragment read offsets: row r, logical slot S=ks*2+lh, phys = S^(r&7)
    int offA[2][4], offB[2][4];
#pragma unroll
    for (int mt = 0; mt < 2; ++mt)
#pragma unroll
        for (int ks = 0; ks < 4; ++ks) {
            const int S = ks * 2 + lh;
            const int rA = wr * 64 + mt * 32 + ln31;
            const int rB = wc * 64 + mt * 32 + ln31;
            offA[mt][ks] = rA * 128 + ((S ^ (rA & 7)) << 4);
            offB[mt][ks] = rB * 128 + ((S ^ (rB & 7)) << 4);
        }

    float4 R0[12], R1[12];          // two NAMED prefetch sets (rule #20)
    float aacc[8] = {0,0,0,0,0,0,0,0};
    float bacc[4] = {0,0,0,0};
    f32x16 acc[2][2] = {};

#define LOADX(kt, S) do {                                                         \
    _Pragma("unroll") for (int j = 0; j < 8; ++j)                                 \
        S[j] = *reinterpret_cast<const float4*>(Axp + (size_t)(32 * j) * Vdim + (kt) * 64); \
    _Pragma("unroll") for (int j = 0; j < 4; ++j)                                 \
        S[8 + j] = *reinterpret_cast<const float4*>(Bxp + (size_t)(32 * j) * Vdim + (kt) * 64); \
} while (0)

#define QWX(S, buf) do {                                                          \
    char* Ad = lds + (buf) * 32768;                                               \
    char* Bd = lds + 65536 + (buf) * 16384;                                       \
    _Pragma("unroll") for (int j = 0; j < 8; ++j) {                               \
        float4 v = S[j];                                                          \
        aacc[j] = fmaf(v.x, v.x, fmaf(v.y, v.y, fmaf(v.z, v.z, fmaf(v.w, v.w, aacc[j])))); \
        B4 w; w.a = __float2bfloat16(v.x); w.b = __float2bfloat16(v.y);           \
        w.c = __float2bfloat16(v.z); w.d = __float2bfloat16(v.w);                 \
        *reinterpret_cast<B4*>(Ad + woffA[j]) = w; }                              \
    _Pragma("unroll") for (int j = 0; j < 4; ++j) {                               \
        float4 v = S[8 + j];                                                      \
        bacc[j] = fmaf(v.x, v.x, fmaf(v.y, v.y, fmaf(v.z, v.z, fmaf(v.w, v.w, bacc[j])))); \
        B4 w; w.a = __float2bfloat16(v.x); w.b = __float2bfloat16(v.y);           \
        w.c = __float2bfloat16(v.z); w.d = __float2bfloat16(v.w);                 \
        *reinterpret_cast<B4*>(Bd + woffB[j]) = w; }                              \
} while (0)

#define MSTEP(buf) do {                                                           \
    const char* Ap = lds + (buf) * 32768;                                         \
    const char* Bp = lds + 65536 + (buf) * 16384;                                 \
    __builtin_amdgcn_s_setprio(1);                                                \
    _Pragma("unroll") for (int ks = 0; ks < 4; ++ks) {                            \
        short8 a0 = *reinterpret_cast<const short8*>(Ap + offA[0][ks]);           \
        short8 a1 = *reinterpret_cast<const short8*>(Ap + offA[1][ks]);           \
        short8 b0 = *reinterpret_cast<const short8*>(Bp + offB[0][ks]);           \
        short8 b1 = *reinterpret_cast<const short8*>(Bp + offB[1][ks]);           \
        acc[0][0] = __builtin_amdgcn_mfma_f32_32x32x16_bf16(a0, b0, acc[0][0], 0, 0, 0); \
        acc[0][1] = __builtin_amdgcn_mfma_f32_32x32x16_bf16(a0, b1, acc[0][1], 0, 0, 0); \
        acc[1][0] = __builtin_amdgcn_mfma_f32_32x32x16_bf16(a1, b0, acc[1][0], 0, 0, 0); \
        acc[1][1] = __builtin_amdgcn_mfma_f32_32x32x16_bf16(a1, b1, acc[1][1], 0, 0, 0); } \
    __builtin_amdgcn_s_setprio(0);                                                \
} while (0)

#define BARRIER do {                                                              \
    asm volatile("s_waitcnt lgkmcnt(0)" ::: "memory");                            \
    __builtin_amdgcn_s_barrier();                                                 \
    CFENCE;                                                                       \
} while (0)

    // prologue: R0 <- step0, write buf0; R1 <- step1
    LOADX(0, R0);
    QWX(R0, 0);
    LOADX(1, R1);
    BARRIER;

    // main loop, unrolled x2 for named ping-pong sets; one barrier per step.
    for (int kt = 0; kt < NT; kt += 2) {
        if (kt + 2 < NT) LOADX(kt + 2, R0);   // issued a full QW+MFMA before use
        if (kt + 1 < NT) QWX(R1, 1);
        CFENCE;
        MSTEP(0);
        CFENCE;
        BARRIER;
        if (kt + 3 < NT) LOADX(kt + 3, R1);
        if (kt + 2 < NT) QWX(R0, 0);
        CFENCE;
        MSTEP(1);
        CFENCE;
        BARRIER;
    }

    // proto fp32 passthrough: rows [bid*8, bid*8+8)
    {
        const int pr = blockIdx.x * 8 + (t >> 6);
        const float* srcp = p + (size_t)pr * Vdim;
        float* dstp = out + (size_t)Mdim * Kdim + (size_t)pr * Vdim;
#pragma unroll
        for (int i = 0; i < 3; ++i)
            *reinterpret_cast<float4*>(dstp + (t & 63) * 4 + i * 256) =
                *reinterpret_cast<const float4*>(srcp + (t & 63) * 4 + i * 256);
    }

    // sumsq reduce through (now dead) LDS; stride 17 -> conflict-free
    float* scr = reinterpret_cast<float*>(lds);          // A [256][17], B at 4352 [128][17]
#pragma unroll
    for (int j = 0; j < 8; ++j) scr[(rg + 32 * j) * 17 + c16] = aacc[j];
#pragma unroll
    for (int j = 0; j < 4; ++j) scr[4352 + (rg + 32 * j) * 17 + c16] = bacc[j];
    BARRIER;
    float* rowsum = reinterpret_cast<float*>(lds + 65536);   // [0,256)=A, [256,384)=B
    if (t < 384) {
        const float* base = scr + (t < 256 ? t * 17 : 4352 + (t - 256) * 17);
        float s = 0.f;
#pragma unroll
        for (int c = 0; c < 16; ++c) s += base[c];
        rowsum[t] = s;
    }
    BARRIER;

    // epilogue. 32x32 C/D: col=lane&31, row=(reg&3)+8*(reg>>2)+4*(lane>>5)
    float ps_[2];
    int col_[2];
#pragma unroll
    for (int nt = 0; nt < 2; ++nt) {
        const int cl = wc * 64 + nt * 32 + ln31;
        col_[nt] = n0 + cl;
        ps_[nt] = rowsum[256 + cl];
    }
#pragma unroll
    for (int mt = 0; mt < 2; ++mt)
#pragma unroll
        for (int reg = 0; reg < 16; ++reg) {
            const int rowl = wr * 64 + mt * 32 + (reg & 3) + 8 * (reg >> 2) + 4 * lh;
            const float xs = rowsum[rowl];
#pragma unroll
            for (int nt = 0; nt < 2; ++nt)
                out[(size_t)(m0 + rowl) * Kdim + col_[nt]] =
                    xs + ps_[nt] - 2.0f * acc[mt][nt][reg];
        }
#undef LOADX
#undef QWX
#undef MSTEP
#undef BARRIER
}

extern "C" void kernel_launch(void* const* d_in, const int* in_sizes, int n_in,
                              void* d_out, int out_size, void* d_ws, size_t ws_size,
                              hipStream_t stream) {
    const float* x = (const float*)d_in[0];   // (16,256,768) fp32
    const float* p = (const float*)d_in[1];   // (2048,768) fp32
    float* out = (float*)d_out;               // distances (4096x2048) + prototypes (2048x768)

    fused_dist<<<256, 512, 0, stream>>>(x, p, out);
}